// Round 15
// baseline (192.023 us; speedup 1.0000x reference)
//
#include <hip/hip_runtime.h>
#include <hip/hip_bf16.h>
#include <cmath>

#define USER_NUM 52643
#define ITEM_NUM 91599
#define NNODE (USER_NUM + ITEM_NUM)   // 144242
#define DDIM 64
#define NBUCK 564                     // ceil(NNODE/256)
#define EPB 8192                      // edges per staging block
#define BCAP 8192                     // max edges per bucket
#define SY 512.0f                     // fp8 y scale
#define SZ 65536.0f                   // fp8 z scale

typedef unsigned int uint32;
typedef unsigned short ushort;

using bf16x8 = __attribute__((ext_vector_type(8))) short;
using f32x4  = __attribute__((ext_vector_type(4))) float;
using f32x2  = __attribute__((ext_vector_type(2))) float;

__device__ __forceinline__ uint32 f2bf(float f) {
    uint32 u = __float_as_uint(f);
    u += 0x7fffu + ((u >> 16) & 1u);   // round-to-nearest-even
    return u >> 16;
}
__device__ __forceinline__ uint32 packbf(float lo, float hi) {
    return (f2bf(hi) << 16) | f2bf(lo);
}

// HW decode: 2 fp8(e4m3fn) bytes (compile-time word sel) -> 2 f32
template <bool HI>
__device__ __forceinline__ f32x2 fp8x2_to_f32(uint32 u) {
    return __builtin_amdgcn_cvt_pk_f32_fp8((int)u, HI);
}

// HW encode: 2 f32 -> 2 fp8 bytes into lo/hi word of old (compile-time sel)
template <bool HI>
__device__ __forceinline__ uint32 fp8pack2(float a, float b, uint32 old) {
    return (uint32)__builtin_amdgcn_cvt_pk_fp8_f32(a, b, (int)old, HI);
}

// ---------------- small utility kernels ----------------

__global__ void init_loss_kernel(float* __restrict__ out, int loss_idx) {
    if (threadIdx.x == 0) out[loss_idx] = 0.0f;
}

// target row list for layer 2: only sampled nodes' g2 is ever read
__global__ void tgt_kernel(const int* __restrict__ user, const int* __restrict__ item_i,
                           const int* __restrict__ item_j, int* __restrict__ tgt, int B) {
    int w = blockIdx.x * 256 + threadIdx.x;
    if (w < B) {
        tgt[w]         = user[w];
        tgt[B + w]     = USER_NUM + item_i[w];
        tgt[2 * B + w] = USER_NUM + item_j[w];
    }
}

// ---------------- bucketed CSR build (all global writes dense) ----------------

__global__ __launch_bounds__(1024) void bucket_count_kernel(
    const int* __restrict__ rows, int* __restrict__ blkcnt, int E)
{
    __shared__ int cnt[NBUCK];
    int t = threadIdx.x;
    for (int i = t; i < NBUCK; i += 1024) cnt[i] = 0;
    __syncthreads();
    int base = blockIdx.x * EPB;
    for (int i = t; i < EPB; i += 1024) {
        int e = base + i;
        if (e < E) atomicAdd(&cnt[rows[e] >> 8], 1);
    }
    __syncthreads();
    for (int i = t; i < NBUCK; i += 1024) blkcnt[blockIdx.x * NBUCK + i] = cnt[i];
}

__global__ __launch_bounds__(256) void bucket_block_scan_kernel(
    int* __restrict__ blkcnt, int* __restrict__ totals, int nblocks)
{
    __shared__ int wsum[4];
    int b = blockIdx.x, t = threadIdx.x;
    int lane = t & 63, wid = t >> 6;
    int c = (t < nblocks) ? blkcnt[t * NBUCK + b] : 0;
    int v = c;
    #pragma unroll
    for (int d = 1; d < 64; d <<= 1) {
        int src = (lane >= d) ? (lane - d) : lane;
        int tmp = __shfl(v, src);
        v += (lane >= d) ? tmp : 0;
    }
    if (lane == 63) wsum[wid] = v;
    __syncthreads();
    int woff = 0;
    for (int w = 0; w < wid; ++w) woff += wsum[w];
    int excl = woff + v - c;
    if (t < nblocks) blkcnt[t * NBUCK + b] = excl;
    if (t == 255) totals[b] = excl + c;
}

__global__ __launch_bounds__(1024) void bucket_off_kernel(
    const int* __restrict__ totals, int* __restrict__ bucket_off,
    int* __restrict__ row_ptr, int E)
{
    __shared__ int s[1024];
    int t = threadIdx.x;
    int v = (t < NBUCK) ? totals[t] : 0;
    s[t] = v;
    __syncthreads();
    #pragma unroll
    for (int d = 1; d < 1024; d <<= 1) {
        int add = (t >= d) ? s[t - d] : 0;
        __syncthreads();
        s[t] += add;
        __syncthreads();
    }
    if (t < NBUCK) bucket_off[t] = s[t] - v;
    if (t == 0) { bucket_off[NBUCK] = E; row_ptr[NNODE] = E; }
}

__global__ __launch_bounds__(1024) void stage_kernel(
    const int* __restrict__ rows, const int* __restrict__ cols,
    const int* __restrict__ blkcnt, const int* __restrict__ bucket_off,
    uint32* __restrict__ staged, int E)
{
    __shared__ int cnt[NBUCK];
    __shared__ int basel[NBUCK];
    int t = threadIdx.x;
    for (int i = t; i < NBUCK; i += 1024) {
        cnt[i] = 0;
        basel[i] = bucket_off[i] + blkcnt[blockIdx.x * NBUCK + i];
    }
    __syncthreads();
    int base = blockIdx.x * EPB;
    for (int i = t; i < EPB; i += 1024) {
        int e = base + i;
        if (e < E) {
            int r = rows[e];
            int bkt = r >> 8;
            int rank = atomicAdd(&cnt[bkt], 1);
            staged[basel[bkt] + rank] = ((uint32)(r & 255) << 18) | (uint32)cols[e];
        }
    }
}

// K6: degrees -> row_ptr/dinv/wout/sback; csr_col written PRE-SHIFTED (col<<5).
__global__ __launch_bounds__(256) void build_kernel(
    const uint32* __restrict__ staged, const int* __restrict__ bucket_off,
    int* __restrict__ row_ptr, int* __restrict__ csr_col,
    float* __restrict__ dinv, float* __restrict__ wout, float* __restrict__ sback)
{
    __shared__ int cnt[256];
    __shared__ int off[256];
    __shared__ int wsum[4];
    __shared__ int colbuf[BCAP];
    int b = blockIdx.x, t = threadIdx.x;
    int lane = t & 63, wid = t >> 6;
    int eoff = bucket_off[b];
    int ecnt = bucket_off[b + 1] - eoff;

    cnt[t] = 0;
    __syncthreads();
    for (int i = t; i < ecnt; i += 256) atomicAdd(&cnt[staged[eoff + i] >> 18], 1);
    __syncthreads();

    int c = cnt[t];
    int v = c;
    #pragma unroll
    for (int d = 1; d < 64; d <<= 1) {
        int src = (lane >= d) ? (lane - d) : lane;
        int tmp = __shfl(v, src);
        v += (lane >= d) ? tmp : 0;
    }
    if (lane == 63) wsum[wid] = v;
    __syncthreads();
    int woff = 0;
    for (int w = 0; w < wid; ++w) woff += wsum[w];
    int excl = woff + v - c;
    off[t] = excl;

    int node = b * 256 + t;
    if (node < NNODE) {
        row_ptr[node] = eoff + excl;
        float df = (float)c;
        float dv = (c > 0) ? (1.0f / sqrtf(df)) : 0.0f;
        dinv[node]  = dv;
        wout[node]  = (c > 0) ? dv : 1.0f;
        sback[node] = (c > 0) ? sqrtf(df) : 1.0f;
    }
    __syncthreads();
    cnt[t] = 0;
    __syncthreads();
    for (int i = t; i < ecnt; i += 256) {
        uint32 w = staged[eoff + i];
        int rl = w >> 18;
        int rank = atomicAdd(&cnt[rl], 1);
        colbuf[off[rl] + rank] = (int)(w & 0x3FFFFu);
    }
    __syncthreads();
    for (int i = t; i < ecnt; i += 256) csr_col[eoff + i] = colbuf[i] << 5;
}

// pack layer-1: bf16 y-pair table (identity/score) + fp8 y+z word table (gathers).
// Zero dummy row NNODE.
__global__ void pack1_kernel(const float* __restrict__ eu, const float* __restrict__ ei,
                             const float* __restrict__ wout,
                             uint32* __restrict__ b1tab, uint32* __restrict__ b2tab,
                             uint32* __restrict__ f1tab, uint32* __restrict__ f2tab) {
    int t = blockIdx.x * 256 + threadIdx.x;     // t = n*32 + d2
    int n = t >> 5, d2 = t & 31;
    if (n > NNODE) return;
    if (n == NNODE) { b1tab[t] = 0; b2tab[t] = 0; f1tab[t] = 0; f2tab[t] = 0; return; }
    const float* xp = (n < USER_NUM) ? (eu + ((size_t)n << 6))
                                     : (ei + (((size_t)n - USER_NUM) << 6));
    float2 x2 = *(const float2*)(xp + 2 * d2);
    float wv = wout[n];
    float y0 = wv * x2.x, y1 = wv * x2.y;
    float z0 = wv * x2.x * x2.x, z1 = wv * x2.y * x2.y;
    b1tab[t] = packbf(y0, y1);
    uint32 w = fp8pack2<false>(SY * y0, SY * y1, 0u);
    w = fp8pack2<true>(SZ * z0, SZ * z1, w);
    f1tab[t] = w;
    (void)d2;
}

// ---------------- fused GNN layer ----------------
// 128-thread blocks (2 waves), 32-row tiles, LDS 8KB -> 16 blocks/CU (32 waves).
// TGT=false: all NNODE rows; TGT=true: rows from tgt[] (layer 2: sampled rows only).
// Gather: dual-row chains; per 2 edges: 1 col shuffle + addr add + 1x 4B fp8 gather
// (y lo16 | z hi16) + 2 HW cvt + 4 adds. Epilogue: MFMA nt-outer (low VGPR).

template <bool TGT>
__global__ __launch_bounds__(128, 8) void gnn_layer_kernel(
    const uint32* __restrict__ ftab, const uint32* __restrict__ btab,
    const int* __restrict__ row_ptr, const int* __restrict__ csr_col,
    const int* __restrict__ tgt,
    const float* __restrict__ sback, const float* __restrict__ dinv,
    const float* __restrict__ wout,
    const float* __restrict__ W, const float* __restrict__ b,
    const float* __restrict__ Wi, const float* __restrict__ bi,
    uint32* __restrict__ obtab, uint32* __restrict__ oftab)
{
    __shared__ unsigned short P1s[32 * 64];   // [row][dim] bf16, byte-col ^ ((row&7)<<4)
    __shared__ unsigned short P2s[32 * 64];

    int tid = threadIdx.x;
    int lane = tid & 63;
    int wid = tid >> 6;       // 0..1
    int h = lane >> 5;        // edge parity
    int d2 = lane & 31;       // dim-pair index
    int base = blockIdx.x * 32;
    int wbase = base + wid * 16;

    int rpS = 0, rpE = 0, trv = 0;
    if (TGT) {
        if (lane < 16) {
            trv = tgt[wbase + lane];        // TGT grid is exact: no bounds check
            rpS = row_ptr[trv];
            rpE = row_ptr[trv + 1];
        }
    } else {
        if (lane <= 16) rpS = row_ptr[min(wbase + lane, NNODE)];
    }

    const float invSY = 1.0f / SY;
    const float invSZ = 1.0f / SZ;
    const int DUMMY = NNODE << 5;

    // ---- gather phase: 16 rows per wave, interleaved pairs ----
    for (int i = 0; i < 16; i += 2) {
        int e0a, e1a, e0b, e1b;
        if (TGT) {
            e0a = __shfl(rpS, i);     e1a = __shfl(rpE, i);
            e0b = __shfl(rpS, i + 1); e1b = __shfl(rpE, i + 1);
        } else {
            e0a = __shfl(rpS, i);
            e1a = __shfl(rpS, i + 1);
            e1b = __shfl(rpS, i + 2);
            e0b = e1a;
        }

        float aA0 = 0.f, aB0 = 0.f, aC0 = 0.f, aD0 = 0.f;
        float aA1 = 0.f, aB1 = 0.f, aC1 = 0.f, aD1 = 0.f;

        int eba = e0a, ebb = e0b;
        while (eba < e1a || ebb < e1b) {
            int ca = DUMMY, cb = DUMMY;
            int ea = eba + lane, eb2 = ebb + lane;
            if (ea < e1a)  ca = csr_col[ea];     // coalesced 4B, pre-shifted col<<5
            if (eb2 < e1b) cb = csr_col[eb2];
            int nna = e1a - eba; nna = (nna < 0) ? 0 : ((nna > 64) ? 64 : nna);
            int nnb = e1b - ebb; nnb = (nnb < 0) ? 0 : ((nnb > 64) ? 64 : nnb);
            int nn = max(nna, nnb);
            for (int k = 0; k < nn; k += 8) {
                uint32 ga[4], gb[4];
                #pragma unroll
                for (int u = 0; u < 4; ++u) {
                    int idx = k + 2 * u + h;
                    int cca = __shfl(ca, idx);           // dummies -> zero row
                    int ccb = __shfl(cb, idx);
                    ga[u] = ftab[(uint32)(cca + d2)];    // 4B: y-pair | z-pair
                    gb[u] = ftab[(uint32)(ccb + d2)];
                }
                #pragma unroll
                for (int u = 0; u < 4; ++u) {
                    f32x2 ya = fp8x2_to_f32<false>(ga[u]);
                    f32x2 za = fp8x2_to_f32<true>(ga[u]);
                    aA0 += ya.x; aB0 += ya.y; aC0 += za.x; aD0 += za.y;
                    f32x2 yb = fp8x2_to_f32<false>(gb[u]);
                    f32x2 zb = fp8x2_to_f32<true>(gb[u]);
                    aA1 += yb.x; aB1 += yb.y; aC1 += zb.x; aD1 += zb.y;
                }
            }
            eba += 64; ebb += 64;
        }

        // combine edge parities
        aA0 += __shfl_xor(aA0, 32); aB0 += __shfl_xor(aB0, 32);
        aC0 += __shfl_xor(aC0, 32); aD0 += __shfl_xor(aD0, 32);
        aA1 += __shfl_xor(aA1, 32); aB1 += __shfl_xor(aB1, 32);
        aC1 += __shfl_xor(aC1, 32); aD1 += __shfl_xor(aD1, 32);

        #pragma unroll
        for (int s = 0; s < 2; ++s) {
            int row, rc;
            if (TGT) { row = __shfl(trv, i + s); rc = row; }
            else     { row = wbase + i + s;      rc = min(row, NNODE); }
            bool valid = TGT || (row < NNODE);
            float dv = valid ? dinv[rc]  : 0.f;
            float sb = valid ? sback[rc] : 0.f;
            uint32 wy = btab[(uint32)(rc * 32 + d2)];
            float xl = __uint_as_float(wy << 16) * sb;          // x = y*sback (exact scale)
            float xh = __uint_as_float(wy & 0xffff0000u) * sb;
            float sA = s ? aA1 : aA0, sB = s ? aB1 : aB0;
            float sC = s ? aC1 : aC0, sD = s ? aD1 : aD0;
            float p1l = fmaf(dv * invSY, sA, xl);   // (L+I)@x
            float p1h = fmaf(dv * invSY, sB, xh);
            float p2l = (dv * invSZ) * sC;          // L@(x*x)
            float p2h = (dv * invSZ) * sD;
            if (h == 0) {
                int rr = wid * 16 + i + s;          // 0..31
                int cbx = (4 * d2) ^ ((rr & 7) << 4);
                *(uint32*)&P1s[rr * 64 + (cbx >> 1)] = packbf(p1l, p1h);
                *(uint32*)&P2s[rr * 64 + (cbx >> 1)] = packbf(p2l, p2h);
            }
        }
    }
    __syncthreads();

    // ---- MFMA phase: wave wid computes cols [32*wid, 32*wid+32) for all 32 rows ----
    // nt-outer to keep VGPR low: per nt (16 cols), load W frags, 8 MFMA, write.
    int l15 = lane & 15;
    int l4  = lane >> 4;
    int n0  = wid * 32;

    #pragma unroll
    for (int nt = 0; nt < 2; ++nt) {
        int coln = n0 + nt * 16 + l15;
        bf16x8 wf[2], wif[2];
        #pragma unroll
        for (int kt = 0; kt < 2; ++kt) {
            const float* wr  = W  + (size_t)coln * 64 + kt * 32 + l4 * 8;
            const float* wir = Wi + (size_t)coln * 64 + kt * 32 + l4 * 8;
            f32x4 a0 = *(const f32x4*)wr;
            f32x4 a1 = *(const f32x4*)(wr + 4);
            f32x4 c0 = *(const f32x4*)wir;
            f32x4 c1 = *(const f32x4*)(wir + 4);
            bf16x8 t0, t1;
            #pragma unroll
            for (int j = 0; j < 4; ++j) {
                t0[j]     = (short)f2bf(a0[j]);
                t0[j + 4] = (short)f2bf(a1[j]);
                t1[j]     = (short)f2bf(c0[j]);
                t1[j + 4] = (short)f2bf(c1[j]);
            }
            wf[kt]  = t0;
            wif[kt] = t1;
        }
        float bias_v = b[coln] + bi[coln];

        f32x4 ac0 = {0.f,0.f,0.f,0.f};
        f32x4 ac1 = {0.f,0.f,0.f,0.f};
        #pragma unroll
        for (int kt = 0; kt < 2; ++kt) {
            {   // mt = 0: rows 0..15
                int rl = l15;
                int cbx = (kt * 64 + l4 * 16) ^ ((rl & 7) << 4);
                int idx = rl * 64 + (cbx >> 1);
                bf16x8 a1f = *(const bf16x8*)&P1s[idx];
                bf16x8 a2f = *(const bf16x8*)&P2s[idx];
                ac0 = __builtin_amdgcn_mfma_f32_16x16x32_bf16(a1f, wf[kt],  ac0, 0, 0, 0);
                ac0 = __builtin_amdgcn_mfma_f32_16x16x32_bf16(a2f, wif[kt], ac0, 0, 0, 0);
            }
            {   // mt = 1: rows 16..31
                int rl = 16 + l15;
                int cbx = (kt * 64 + l4 * 16) ^ ((rl & 7) << 4);
                int idx = rl * 64 + (cbx >> 1);
                bf16x8 a1f = *(const bf16x8*)&P1s[idx];
                bf16x8 a2f = *(const bf16x8*)&P2s[idx];
                ac1 = __builtin_amdgcn_mfma_f32_16x16x32_bf16(a1f, wf[kt],  ac1, 0, 0, 0);
                ac1 = __builtin_amdgcn_mfma_f32_16x16x32_bf16(a2f, wif[kt], ac1, 0, 0, 0);
            }
        }

        // C layout: col = lane&15 (-> coln), row = (lane>>4)*4 + j (+ mt*16)
        #pragma unroll
        for (int mt = 0; mt < 2; ++mt) {
            f32x4 A = mt ? ac1 : ac0;
            #pragma unroll
            for (int j = 0; j < 4; ++j) {
                int ridx = base + mt * 16 + l4 * 4 + j;
                int r = TGT ? tgt[ridx] : ridx;
                bool valid = TGT || (r < NNODE);
                float o = fmaxf(A[j] + bias_v, 0.0f);
                float wsc = valid ? wout[r] : 0.0f;
                float oy = o * wsc;          // wout*o
                float oz = oy * o;           // wout*o^2
                float oyn = __shfl_xor(oy, 1);
                float ozn = __shfl_xor(oz, 1);
                if (((l15 & 1) == 0) && valid) {
                    size_t oidx = (size_t)r * 32 + (coln >> 1);
                    obtab[oidx] = packbf(oy, oyn);
                    if (oftab) {
                        uint32 w = fp8pack2<false>(SY * oy, SY * oyn, 0u);
                        w = fp8pack2<true>(SZ * oz, SZ * ozn, w);
                        oftab[oidx] = w;
                    }
                }
            }
        }
    }
}

// ---------------- scoring + loss ----------------

__global__ __launch_bounds__(256) void score_kernel(
    const int* __restrict__ user, const int* __restrict__ item_i,
    const int* __restrict__ item_j,
    const float* __restrict__ eu, const float* __restrict__ ei,
    const uint32* __restrict__ g1tab, const uint32* __restrict__ g2tab,
    const float* __restrict__ sback,
    float* __restrict__ out, int B, int nwaves)
{
    int tid = threadIdx.x;
    int lane = tid & 63;
    int wv = tid >> 6;
    int gw = blockIdx.x * 4 + wv;
    int h = lane >> 5, d2 = lane & 31;

    float spacc = 0.0f;
    for (int w = gw; w < B; w += nwaves) {
        int u  = user[w];
        int i0 = item_i[w];
        int j0 = item_j[w];
        int ii = USER_NUM + i0;
        int jj = USER_NUM + j0;

        float e0u = eu[(size_t)u  * DDIM + lane];
        float e0i = ei[(size_t)i0 * DDIM + lane];
        float e0j = ei[(size_t)j0 * DDIM + lane];
        float di = e0u * e0i;
        float dj = e0u * e0j;

        const uint32* tb = h ? g2tab : g1tab;
        float su = sback[u], si2 = sback[ii], sj2 = sback[jj];
        uint32 wu = tb[(size_t)u  * 32 + d2];
        uint32 wi = tb[(size_t)ii * 32 + d2];
        uint32 wj = tb[(size_t)jj * 32 + d2];
        float u0 = __uint_as_float(wu << 16) * su,   u1 = __uint_as_float(wu & 0xffff0000u) * su;
        float i0f = __uint_as_float(wi << 16) * si2, i1f = __uint_as_float(wi & 0xffff0000u) * si2;
        float j0f = __uint_as_float(wj << 16) * sj2, j1f = __uint_as_float(wj & 0xffff0000u) * sj2;
        di += u0 * i0f + u1 * i1f;
        dj += u0 * j0f + u1 * j1f;

        for (int off = 32; off; off >>= 1) {
            di += __shfl_xor(di, off);
            dj += __shfl_xor(dj, off);
        }
        if (lane == 0) {
            out[w] = di;
            out[B + w] = dj;
            float x = di - dj;
            spacc += fmaxf(-x, 0.0f) + log1pf(expf(-fabsf(x)));   // softplus(-x)
        }
    }

    __shared__ float sred[4];
    if (lane == 0) sred[wv] = spacc;
    __syncthreads();
    if (tid == 0)
        atomicAdd(&out[2 * B], sred[0] + sred[1] + sred[2] + sred[3]);
}

// ---------------- launch ----------------

extern "C" void kernel_launch(void* const* d_in, const int* in_sizes, int n_in,
                              void* d_out, int out_size, void* d_ws, size_t ws_size,
                              hipStream_t stream) {
    const int*   user       = (const int*)d_in[0];
    const int*   item_i     = (const int*)d_in[1];
    const int*   item_j     = (const int*)d_in[2];
    const int*   rows       = (const int*)d_in[3];
    const int*   cols       = (const int*)d_in[4];
    const float* embed_user = (const float*)d_in[6];
    const float* embed_item = (const float*)d_in[7];
    const float* W1  = (const float*)d_in[8];
    const float* b1  = (const float*)d_in[9];
    const float* Wi1 = (const float*)d_in[10];
    const float* bi1 = (const float*)d_in[11];
    const float* W2  = (const float*)d_in[12];
    const float* b2  = (const float*)d_in[13];
    const float* Wi2 = (const float*)d_in[14];
    const float* bi2 = (const float*)d_in[15];

    int B = in_sizes[0];
    int E = in_sizes[3];
    float* out = (float*)d_out;

    char* ws = (char*)d_ws;
    size_t off = 0;
    auto alloc = [&](size_t bytes) -> void* {
        void* p = ws + off;
        off += (bytes + 255) & ~(size_t)255;
        return p;
    };
    uint32* b1tab    = (uint32*)alloc((size_t)(NNODE + 1) * 32 * 4);   // bf16 y tables
    uint32* b2tab    = (uint32*)alloc((size_t)(NNODE + 1) * 32 * 4);
    uint32* b3tab    = (uint32*)alloc((size_t)(NNODE + 1) * 32 * 4);
    uint32* f1tab    = (uint32*)alloc((size_t)(NNODE + 1) * 32 * 4);   // fp8 y+z tables
    uint32* f2tab    = (uint32*)alloc((size_t)(NNODE + 1) * 32 * 4);
    int*    row_ptr  = (int*)alloc((size_t)(NNODE + 1) * 4);
    int*    csr_col  = (int*)alloc((size_t)E * 4);
    uint32* staged   = (uint32*)alloc((size_t)E * 4);
    float*  dinv     = (float*)alloc((size_t)NNODE * 4);
    float*  wout     = (float*)alloc((size_t)NNODE * 4);
    float*  sback    = (float*)alloc((size_t)NNODE * 4);
    int*    totals   = (int*)alloc((size_t)NBUCK * 4);
    int*    bucket_off = (int*)alloc((size_t)(NBUCK + 1) * 4);
    int*    tgt      = (int*)alloc((size_t)(3 * B) * 4);
    int     nblocks  = (E + EPB - 1) / EPB;            // 245
    int*    blkcnt   = (int*)alloc((size_t)nblocks * NBUCK * 4);

    bucket_count_kernel<<<nblocks, 1024, 0, stream>>>(rows, blkcnt, E);
    bucket_block_scan_kernel<<<NBUCK, 256, 0, stream>>>(blkcnt, totals, nblocks);
    bucket_off_kernel<<<1, 1024, 0, stream>>>(totals, bucket_off, row_ptr, E);
    stage_kernel<<<nblocks, 1024, 0, stream>>>(rows, cols, blkcnt, bucket_off, staged, E);
    build_kernel<<<NBUCK, 256, 0, stream>>>(staged, bucket_off, row_ptr, csr_col,
                                            dinv, wout, sback);
    tgt_kernel<<<(B + 255) / 256, 256, 0, stream>>>(user, item_i, item_j, tgt, B);

    pack1_kernel<<<((NNODE + 1) * 32 + 255) / 256, 256, 0, stream>>>(
        embed_user, embed_item, wout, b1tab, b2tab, f1tab, f2tab);

    const int GNNB = (NNODE + 31) / 32;   // 4508
    gnn_layer_kernel<false><<<GNNB, 128, 0, stream>>>(
        f1tab, b1tab, row_ptr, csr_col, nullptr, sback, dinv, wout,
        W1, b1, Wi1, bi1, b2tab, f2tab);
    const int TGTB = (3 * B + 31) / 32;   // 768
    gnn_layer_kernel<true><<<TGTB, 128, 0, stream>>>(
        f2tab, b2tab, row_ptr, csr_col, tgt, sback, dinv, wout,
        W2, b2, Wi2, bi2, b3tab, nullptr);

    init_loss_kernel<<<1, 64, 0, stream>>>(out, 2 * B);
    const int SCORE_BLOCKS = 256;                      // 1024 waves, 8 samples each
    score_kernel<<<SCORE_BLOCKS, 256, 0, stream>>>(
        user, item_i, item_j, embed_user, embed_item, b2tab, b3tab, sback,
        out, B, SCORE_BLOCKS * 4);
}

// Round 16
// 176.804 us; speedup vs baseline: 1.0861x; 1.0861x over previous
//
#include <hip/hip_runtime.h>
#include <hip/hip_bf16.h>
#include <cmath>

#define USER_NUM 52643
#define ITEM_NUM 91599
#define NNODE (USER_NUM + ITEM_NUM)   // 144242
#define DDIM 64
#define NBUCK 564                     // ceil(NNODE/256)
#define EPB 8192                      // edges per staging block
#define BCAP 8192                     // max edges per bucket
#define SY 512.0f                     // fp8 y scale
#define SZ 65536.0f                   // fp8 z scale

typedef unsigned int uint32;
typedef unsigned short ushort;

using bf16x8 = __attribute__((ext_vector_type(8))) short;
using f32x4  = __attribute__((ext_vector_type(4))) float;
using f32x2  = __attribute__((ext_vector_type(2))) float;

__device__ __forceinline__ uint32 f2bf(float f) {
    uint32 u = __float_as_uint(f);
    u += 0x7fffu + ((u >> 16) & 1u);   // round-to-nearest-even
    return u >> 16;
}
__device__ __forceinline__ uint32 packbf(float lo, float hi) {
    return (f2bf(hi) << 16) | f2bf(lo);
}

// HW decode: 2 fp8(e4m3fn) bytes (compile-time word sel) -> 2 f32
template <bool HI>
__device__ __forceinline__ f32x2 fp8x2_to_f32(uint32 u) {
    return __builtin_amdgcn_cvt_pk_f32_fp8((int)u, HI);
}

// HW encode: 2 f32 -> 2 fp8 bytes into lo/hi word of old (compile-time sel)
template <bool HI>
__device__ __forceinline__ uint32 fp8pack2(float a, float b, uint32 old) {
    return (uint32)__builtin_amdgcn_cvt_pk_fp8_f32(a, b, (int)old, HI);
}

// ---------------- bucketed CSR build (all global writes dense) ----------------

__global__ __launch_bounds__(1024) void bucket_count_kernel(
    const int* __restrict__ rows, int* __restrict__ blkcnt, int E)
{
    __shared__ int cnt[NBUCK];
    int t = threadIdx.x;
    for (int i = t; i < NBUCK; i += 1024) cnt[i] = 0;
    __syncthreads();
    int base = blockIdx.x * EPB;
    for (int i = t; i < EPB; i += 1024) {
        int e = base + i;
        if (e < E) atomicAdd(&cnt[rows[e] >> 8], 1);
    }
    __syncthreads();
    for (int i = t; i < NBUCK; i += 1024) blkcnt[blockIdx.x * NBUCK + i] = cnt[i];
}

__global__ __launch_bounds__(256) void bucket_block_scan_kernel(
    int* __restrict__ blkcnt, int* __restrict__ totals, int nblocks)
{
    __shared__ int wsum[4];
    int b = blockIdx.x, t = threadIdx.x;
    int lane = t & 63, wid = t >> 6;
    int c = (t < nblocks) ? blkcnt[t * NBUCK + b] : 0;
    int v = c;
    #pragma unroll
    for (int d = 1; d < 64; d <<= 1) {
        int src = (lane >= d) ? (lane - d) : lane;
        int tmp = __shfl(v, src);
        v += (lane >= d) ? tmp : 0;
    }
    if (lane == 63) wsum[wid] = v;
    __syncthreads();
    int woff = 0;
    for (int w = 0; w < wid; ++w) woff += wsum[w];
    int excl = woff + v - c;
    if (t < nblocks) blkcnt[t * NBUCK + b] = excl;
    if (t == 255) totals[b] = excl + c;
}

__global__ __launch_bounds__(1024) void bucket_off_kernel(
    const int* __restrict__ totals, int* __restrict__ bucket_off,
    int* __restrict__ row_ptr, int E)
{
    __shared__ int s[1024];
    int t = threadIdx.x;
    int v = (t < NBUCK) ? totals[t] : 0;
    s[t] = v;
    __syncthreads();
    #pragma unroll
    for (int d = 1; d < 1024; d <<= 1) {
        int add = (t >= d) ? s[t - d] : 0;
        __syncthreads();
        s[t] += add;
        __syncthreads();
    }
    if (t < NBUCK) bucket_off[t] = s[t] - v;
    if (t == 0) { bucket_off[NBUCK] = E; row_ptr[NNODE] = E; }
}

__global__ __launch_bounds__(1024) void stage_kernel(
    const int* __restrict__ rows, const int* __restrict__ cols,
    const int* __restrict__ blkcnt, const int* __restrict__ bucket_off,
    uint32* __restrict__ staged, int E)
{
    __shared__ int cnt[NBUCK];
    __shared__ int basel[NBUCK];
    int t = threadIdx.x;
    for (int i = t; i < NBUCK; i += 1024) {
        cnt[i] = 0;
        basel[i] = bucket_off[i] + blkcnt[blockIdx.x * NBUCK + i];
    }
    __syncthreads();
    int base = blockIdx.x * EPB;
    for (int i = t; i < EPB; i += 1024) {
        int e = base + i;
        if (e < E) {
            int r = rows[e];
            int bkt = r >> 8;
            int rank = atomicAdd(&cnt[bkt], 1);
            staged[basel[bkt] + rank] = ((uint32)(r & 255) << 18) | (uint32)cols[e];
        }
    }
}

// K6: degrees -> row_ptr/dinv/wout/sback; csr_col written PRE-SHIFTED (col<<5).
__global__ __launch_bounds__(256) void build_kernel(
    const uint32* __restrict__ staged, const int* __restrict__ bucket_off,
    int* __restrict__ row_ptr, int* __restrict__ csr_col,
    float* __restrict__ dinv, float* __restrict__ wout, float* __restrict__ sback)
{
    __shared__ int cnt[256];
    __shared__ int off[256];
    __shared__ int wsum[4];
    __shared__ int colbuf[BCAP];
    int b = blockIdx.x, t = threadIdx.x;
    int lane = t & 63, wid = t >> 6;
    int eoff = bucket_off[b];
    int ecnt = bucket_off[b + 1] - eoff;

    cnt[t] = 0;
    __syncthreads();
    for (int i = t; i < ecnt; i += 256) atomicAdd(&cnt[staged[eoff + i] >> 18], 1);
    __syncthreads();

    int c = cnt[t];
    int v = c;
    #pragma unroll
    for (int d = 1; d < 64; d <<= 1) {
        int src = (lane >= d) ? (lane - d) : lane;
        int tmp = __shfl(v, src);
        v += (lane >= d) ? tmp : 0;
    }
    if (lane == 63) wsum[wid] = v;
    __syncthreads();
    int woff = 0;
    for (int w = 0; w < wid; ++w) woff += wsum[w];
    int excl = woff + v - c;
    off[t] = excl;

    int node = b * 256 + t;
    if (node < NNODE) {
        row_ptr[node] = eoff + excl;
        float df = (float)c;
        float dv = (c > 0) ? (1.0f / sqrtf(df)) : 0.0f;
        dinv[node]  = dv;
        wout[node]  = (c > 0) ? dv : 1.0f;
        sback[node] = (c > 0) ? sqrtf(df) : 1.0f;
    }
    __syncthreads();
    cnt[t] = 0;
    __syncthreads();
    for (int i = t; i < ecnt; i += 256) {
        uint32 w = staged[eoff + i];
        int rl = w >> 18;
        int rank = atomicAdd(&cnt[rl], 1);
        colbuf[off[rl] + rank] = (int)(w & 0x3FFFFu);
    }
    __syncthreads();
    for (int i = t; i < ecnt; i += 256) csr_col[eoff + i] = colbuf[i] << 5;
}

// pack layer-1: bf16 y-pair table (identity/score) + fp8 y+z word table (gathers).
// Zero dummy row NNODE. Also (folded): build tgt[] list and zero the loss slot.
__global__ void pack1_kernel(const float* __restrict__ eu, const float* __restrict__ ei,
                             const float* __restrict__ wout,
                             uint32* __restrict__ b1tab, uint32* __restrict__ b2tab,
                             uint32* __restrict__ f1tab, uint32* __restrict__ f2tab,
                             const int* __restrict__ user, const int* __restrict__ item_i,
                             const int* __restrict__ item_j, int* __restrict__ tgt,
                             float* __restrict__ out, int B) {
    int t = blockIdx.x * 256 + threadIdx.x;     // t = n*32 + d2
    // folded: tgt list + loss init (independent of table packing)
    if (t < 3 * B) {
        int w = (t < B) ? t : ((t < 2 * B) ? t - B : t - 2 * B);
        int val = (t < B) ? user[w] : ((t < 2 * B) ? USER_NUM + item_i[w]
                                                   : USER_NUM + item_j[w]);
        tgt[t] = val;
    }
    if (t == 0) out[2 * B] = 0.0f;

    int n = t >> 5, d2 = t & 31;
    if (n > NNODE) return;
    if (n == NNODE) { b1tab[t] = 0; b2tab[t] = 0; f1tab[t] = 0; f2tab[t] = 0; return; }
    const float* xp = (n < USER_NUM) ? (eu + ((size_t)n << 6))
                                     : (ei + (((size_t)n - USER_NUM) << 6));
    float2 x2 = *(const float2*)(xp + 2 * d2);
    float wv = wout[n];
    float y0 = wv * x2.x, y1 = wv * x2.y;
    float z0 = wv * x2.x * x2.x, z1 = wv * x2.y * x2.y;
    b1tab[t] = packbf(y0, y1);
    uint32 w = fp8pack2<false>(SY * y0, SY * y1, 0u);
    w = fp8pack2<true>(SZ * z0, SZ * z1, w);
    f1tab[t] = w;
    (void)d2;
}

// ---------------- fused GNN layer ----------------
// R14 structure (best measured). 256 threads / 4 waves / 64-row tiles.
// TGT=false: all NNODE rows; TGT=true: rows from tgt[] (layer 2: sampled rows only).
// Gather: dual-row chains; per 2 edges: 1 col shuffle + addr add + 1x 4B fp8 gather
// (y lo16 | z hi16) + 2 HW cvt + 4 adds. Epilogue: MFMA; bf16 (+fp8) tables.

template <bool TGT>
__global__ __launch_bounds__(256, 8) void gnn_layer_kernel(
    const uint32* __restrict__ ftab, const uint32* __restrict__ btab,
    const int* __restrict__ row_ptr, const int* __restrict__ csr_col,
    const int* __restrict__ tgt,
    const float* __restrict__ sback, const float* __restrict__ dinv,
    const float* __restrict__ wout,
    const float* __restrict__ W, const float* __restrict__ b,
    const float* __restrict__ Wi, const float* __restrict__ bi,
    uint32* __restrict__ obtab, uint32* __restrict__ oftab)
{
    __shared__ unsigned short P1s[64 * 64];   // [row][dim] bf16, byte-col ^ ((row&7)<<4)
    __shared__ unsigned short P2s[64 * 64];

    int tid = threadIdx.x;
    int lane = tid & 63;
    int wid = tid >> 6;
    int h = lane >> 5;        // edge parity
    int d2 = lane & 31;       // dim-pair index
    int base = blockIdx.x * 64;
    int wbase = base + wid * 16;

    int rpS = 0, rpE = 0, trv = 0;
    if (TGT) {
        if (lane < 16) {
            trv = tgt[wbase + lane];        // TGT grid is exact: no bounds check
            rpS = row_ptr[trv];
            rpE = row_ptr[trv + 1];
        }
    } else {
        if (lane <= 16) rpS = row_ptr[min(wbase + lane, NNODE)];
    }

    const float invSY = 1.0f / SY;
    const float invSZ = 1.0f / SZ;
    const int DUMMY = NNODE << 5;

    // ---- gather phase: 16 rows per wave, interleaved pairs ----
    for (int i = 0; i < 16; i += 2) {
        int e0a, e1a, e0b, e1b;
        if (TGT) {
            e0a = __shfl(rpS, i);     e1a = __shfl(rpE, i);
            e0b = __shfl(rpS, i + 1); e1b = __shfl(rpE, i + 1);
        } else {
            e0a = __shfl(rpS, i);
            e1a = __shfl(rpS, i + 1);
            e1b = __shfl(rpS, i + 2);
            e0b = e1a;
        }

        float aA0 = 0.f, aB0 = 0.f, aC0 = 0.f, aD0 = 0.f;
        float aA1 = 0.f, aB1 = 0.f, aC1 = 0.f, aD1 = 0.f;

        int eba = e0a, ebb = e0b;
        while (eba < e1a || ebb < e1b) {
            int ca = DUMMY, cb = DUMMY;
            int ea = eba + lane, eb2 = ebb + lane;
            if (ea < e1a)  ca = csr_col[ea];     // coalesced 4B, pre-shifted col<<5
            if (eb2 < e1b) cb = csr_col[eb2];
            int nna = e1a - eba; nna = (nna < 0) ? 0 : ((nna > 64) ? 64 : nna);
            int nnb = e1b - ebb; nnb = (nnb < 0) ? 0 : ((nnb > 64) ? 64 : nnb);
            int nn = max(nna, nnb);
            for (int k = 0; k < nn; k += 8) {
                uint32 ga[4], gb[4];
                #pragma unroll
                for (int u = 0; u < 4; ++u) {
                    int idx = k + 2 * u + h;
                    int cca = __shfl(ca, idx);           // dummies -> zero row
                    int ccb = __shfl(cb, idx);
                    ga[u] = ftab[(uint32)(cca + d2)];    // 4B: y-pair | z-pair
                    gb[u] = ftab[(uint32)(ccb + d2)];
                }
                #pragma unroll
                for (int u = 0; u < 4; ++u) {
                    f32x2 ya = fp8x2_to_f32<false>(ga[u]);
                    f32x2 za = fp8x2_to_f32<true>(ga[u]);
                    aA0 += ya.x; aB0 += ya.y; aC0 += za.x; aD0 += za.y;
                    f32x2 yb = fp8x2_to_f32<false>(gb[u]);
                    f32x2 zb = fp8x2_to_f32<true>(gb[u]);
                    aA1 += yb.x; aB1 += yb.y; aC1 += zb.x; aD1 += zb.y;
                }
            }
            eba += 64; ebb += 64;
        }

        // combine edge parities
        aA0 += __shfl_xor(aA0, 32); aB0 += __shfl_xor(aB0, 32);
        aC0 += __shfl_xor(aC0, 32); aD0 += __shfl_xor(aD0, 32);
        aA1 += __shfl_xor(aA1, 32); aB1 += __shfl_xor(aB1, 32);
        aC1 += __shfl_xor(aC1, 32); aD1 += __shfl_xor(aD1, 32);

        #pragma unroll
        for (int s = 0; s < 2; ++s) {
            int row, rc;
            if (TGT) { row = __shfl(trv, i + s); rc = row; }
            else     { row = wbase + i + s;      rc = min(row, NNODE); }
            bool valid = TGT || (row < NNODE);
            float dv = valid ? dinv[rc]  : 0.f;
            float sb = valid ? sback[rc] : 0.f;
            uint32 wy = btab[(uint32)(rc * 32 + d2)];
            float xl = __uint_as_float(wy << 16) * sb;          // x = y*sback (exact scale)
            float xh = __uint_as_float(wy & 0xffff0000u) * sb;
            float sA = s ? aA1 : aA0, sB = s ? aB1 : aB0;
            float sC = s ? aC1 : aC0, sD = s ? aD1 : aD0;
            float p1l = fmaf(dv * invSY, sA, xl);   // (L+I)@x
            float p1h = fmaf(dv * invSY, sB, xh);
            float p2l = (dv * invSZ) * sC;          // L@(x*x)
            float p2h = (dv * invSZ) * sD;
            if (h == 0) {
                int rr = wid * 16 + i + s;
                int cbx = (4 * d2) ^ ((rr & 7) << 4);
                *(uint32*)&P1s[rr * 64 + (cbx >> 1)] = packbf(p1l, p1h);
                *(uint32*)&P2s[rr * 64 + (cbx >> 1)] = packbf(p2l, p2h);
            }
        }
    }
    __syncthreads();

    // ---- MFMA phase: wave wid computes cols [16*wid, 16*wid+16) for all 64 rows ----
    int l15 = lane & 15;
    int l4  = lane >> 4;
    int n0  = wid * 16;

    bf16x8 wf[2], wif[2];
    #pragma unroll
    for (int kt = 0; kt < 2; ++kt) {
        const float* wr  = W  + (size_t)(n0 + l15) * 64 + kt * 32 + l4 * 8;
        const float* wir = Wi + (size_t)(n0 + l15) * 64 + kt * 32 + l4 * 8;
        f32x4 a0 = *(const f32x4*)wr;
        f32x4 a1 = *(const f32x4*)(wr + 4);
        f32x4 c0 = *(const f32x4*)wir;
        f32x4 c1 = *(const f32x4*)(wir + 4);
        bf16x8 t0, t1;
        #pragma unroll
        for (int j = 0; j < 4; ++j) {
            t0[j]     = (short)f2bf(a0[j]);
            t0[j + 4] = (short)f2bf(a1[j]);
            t1[j]     = (short)f2bf(c0[j]);
            t1[j + 4] = (short)f2bf(c1[j]);
        }
        wf[kt]  = t0;
        wif[kt] = t1;
    }
    float bias_v = b[n0 + l15] + bi[n0 + l15];

    f32x4 acc0 = {0.f,0.f,0.f,0.f}, acc1v = {0.f,0.f,0.f,0.f};
    f32x4 acc2v = {0.f,0.f,0.f,0.f}, acc3 = {0.f,0.f,0.f,0.f};
    f32x4* accp[4] = {&acc0, &acc1v, &acc2v, &acc3};

    #pragma unroll
    for (int mt = 0; mt < 4; ++mt) {
        #pragma unroll
        for (int kt = 0; kt < 2; ++kt) {
            int rl = mt * 16 + l15;
            int cbx = (kt * 64 + l4 * 16) ^ ((rl & 7) << 4);
            int idx = rl * 64 + (cbx >> 1);
            bf16x8 a1f = *(const bf16x8*)&P1s[idx];
            bf16x8 a2f = *(const bf16x8*)&P2s[idx];
            *accp[mt] = __builtin_amdgcn_mfma_f32_16x16x32_bf16(a1f, wf[kt],  *accp[mt], 0, 0, 0);
            *accp[mt] = __builtin_amdgcn_mfma_f32_16x16x32_bf16(a2f, wif[kt], *accp[mt], 0, 0, 0);
        }
    }

    // C layout: col = lane&15, row = (lane>>4)*4 + j (+ mt*16). Write tables.
    #pragma unroll
    for (int mt = 0; mt < 4; ++mt) {
        #pragma unroll
        for (int j = 0; j < 4; ++j) {
            int ridx = base + mt * 16 + l4 * 4 + j;
            int r = TGT ? tgt[ridx] : ridx;
            bool valid = TGT || (r < NNODE);
            float o = fmaxf((*accp[mt])[j] + bias_v, 0.0f);
            float wsc = valid ? wout[r] : 0.0f;
            float oy = o * wsc;          // wout*o
            float oz = oy * o;           // wout*o^2
            float oyn = __shfl_xor(oy, 1);
            float ozn = __shfl_xor(oz, 1);
            if (((l15 & 1) == 0) && valid) {
                size_t oidx = (size_t)r * 32 + ((n0 + l15) >> 1);
                obtab[oidx] = packbf(oy, oyn);
                if (oftab) {
                    uint32 w = fp8pack2<false>(SY * oy, SY * oyn, 0u);
                    w = fp8pack2<true>(SZ * oz, SZ * ozn, w);
                    oftab[oidx] = w;
                }
            }
        }
    }
}

// ---------------- scoring + loss ----------------

__global__ __launch_bounds__(256) void score_kernel(
    const int* __restrict__ user, const int* __restrict__ item_i,
    const int* __restrict__ item_j,
    const float* __restrict__ eu, const float* __restrict__ ei,
    const uint32* __restrict__ g1tab, const uint32* __restrict__ g2tab,
    const float* __restrict__ sback,
    float* __restrict__ out, int B, int nwaves)
{
    int tid = threadIdx.x;
    int lane = tid & 63;
    int wv = tid >> 6;
    int gw = blockIdx.x * 4 + wv;
    int h = lane >> 5, d2 = lane & 31;

    float spacc = 0.0f;
    for (int w = gw; w < B; w += nwaves) {
        int u  = user[w];
        int i0 = item_i[w];
        int j0 = item_j[w];
        int ii = USER_NUM + i0;
        int jj = USER_NUM + j0;

        float e0u = eu[(size_t)u  * DDIM + lane];
        float e0i = ei[(size_t)i0 * DDIM + lane];
        float e0j = ei[(size_t)j0 * DDIM + lane];
        float di = e0u * e0i;
        float dj = e0u * e0j;

        const uint32* tb = h ? g2tab : g1tab;
        float su = sback[u], si2 = sback[ii], sj2 = sback[jj];
        uint32 wu = tb[(size_t)u  * 32 + d2];
        uint32 wi = tb[(size_t)ii * 32 + d2];
        uint32 wj = tb[(size_t)jj * 32 + d2];
        float u0 = __uint_as_float(wu << 16) * su,   u1 = __uint_as_float(wu & 0xffff0000u) * su;
        float i0f = __uint_as_float(wi << 16) * si2, i1f = __uint_as_float(wi & 0xffff0000u) * si2;
        float j0f = __uint_as_float(wj << 16) * sj2, j1f = __uint_as_float(wj & 0xffff0000u) * sj2;
        di += u0 * i0f + u1 * i1f;
        dj += u0 * j0f + u1 * j1f;

        for (int off = 32; off; off >>= 1) {
            di += __shfl_xor(di, off);
            dj += __shfl_xor(dj, off);
        }
        if (lane == 0) {
            out[w] = di;
            out[B + w] = dj;
            float x = di - dj;
            spacc += fmaxf(-x, 0.0f) + log1pf(expf(-fabsf(x)));   // softplus(-x)
        }
    }

    __shared__ float sred[4];
    if (lane == 0) sred[wv] = spacc;
    __syncthreads();
    if (tid == 0)
        atomicAdd(&out[2 * B], sred[0] + sred[1] + sred[2] + sred[3]);
}

// ---------------- launch ----------------

extern "C" void kernel_launch(void* const* d_in, const int* in_sizes, int n_in,
                              void* d_out, int out_size, void* d_ws, size_t ws_size,
                              hipStream_t stream) {
    const int*   user       = (const int*)d_in[0];
    const int*   item_i     = (const int*)d_in[1];
    const int*   item_j     = (const int*)d_in[2];
    const int*   rows       = (const int*)d_in[3];
    const int*   cols       = (const int*)d_in[4];
    const float* embed_user = (const float*)d_in[6];
    const float* embed_item = (const float*)d_in[7];
    const float* W1  = (const float*)d_in[8];
    const float* b1  = (const float*)d_in[9];
    const float* Wi1 = (const float*)d_in[10];
    const float* bi1 = (const float*)d_in[11];
    const float* W2  = (const float*)d_in[12];
    const float* b2  = (const float*)d_in[13];
    const float* Wi2 = (const float*)d_in[14];
    const float* bi2 = (const float*)d_in[15];

    int B = in_sizes[0];
    int E = in_sizes[3];
    float* out = (float*)d_out;

    char* ws = (char*)d_ws;
    size_t off = 0;
    auto alloc = [&](size_t bytes) -> void* {
        void* p = ws + off;
        off += (bytes + 255) & ~(size_t)255;
        return p;
    };
    uint32* b1tab    = (uint32*)alloc((size_t)(NNODE + 1) * 32 * 4);   // bf16 y tables
    uint32* b2tab    = (uint32*)alloc((size_t)(NNODE + 1) * 32 * 4);
    uint32* b3tab    = (uint32*)alloc((size_t)(NNODE + 1) * 32 * 4);
    uint32* f1tab    = (uint32*)alloc((size_t)(NNODE + 1) * 32 * 4);   // fp8 y+z tables
    uint32* f2tab    = (uint32*)alloc((size_t)(NNODE + 1) * 32 * 4);
    int*    row_ptr  = (int*)alloc((size_t)(NNODE + 1) * 4);
    int*    csr_col  = (int*)alloc((size_t)E * 4);
    uint32* staged   = (uint32*)alloc((size_t)E * 4);
    float*  dinv     = (float*)alloc((size_t)NNODE * 4);
    float*  wout     = (float*)alloc((size_t)NNODE * 4);
    float*  sback    = (float*)alloc((size_t)NNODE * 4);
    int*    totals   = (int*)alloc((size_t)NBUCK * 4);
    int*    bucket_off = (int*)alloc((size_t)(NBUCK + 1) * 4);
    int*    tgt      = (int*)alloc((size_t)(3 * B) * 4);
    int     nblocks  = (E + EPB - 1) / EPB;            // 245
    int*    blkcnt   = (int*)alloc((size_t)nblocks * NBUCK * 4);

    bucket_count_kernel<<<nblocks, 1024, 0, stream>>>(rows, blkcnt, E);
    bucket_block_scan_kernel<<<NBUCK, 256, 0, stream>>>(blkcnt, totals, nblocks);
    bucket_off_kernel<<<1, 1024, 0, stream>>>(totals, bucket_off, row_ptr, E);
    stage_kernel<<<nblocks, 1024, 0, stream>>>(rows, cols, blkcnt, bucket_off, staged, E);
    build_kernel<<<NBUCK, 256, 0, stream>>>(staged, bucket_off, row_ptr, csr_col,
                                            dinv, wout, sback);

    pack1_kernel<<<((NNODE + 1) * 32 + 255) / 256, 256, 0, stream>>>(
        embed_user, embed_item, wout, b1tab, b2tab, f1tab, f2tab,
        user, item_i, item_j, tgt, out, B);

    const int GNNB = (NNODE + 63) / 64;   // 2254
    gnn_layer_kernel<false><<<GNNB, 256, 0, stream>>>(
        f1tab, b1tab, row_ptr, csr_col, nullptr, sback, dinv, wout,
        W1, b1, Wi1, bi1, b2tab, f2tab);
    const int TGTB = (3 * B + 63) / 64;   // 384
    gnn_layer_kernel<true><<<TGTB, 256, 0, stream>>>(
        f2tab, b2tab, row_ptr, csr_col, tgt, sback, dinv, wout,
        W2, b2, Wi2, bi2, b3tab, nullptr);

    const int SCORE_BLOCKS = 256;                      // 1024 waves, 8 samples each
    score_kernel<<<SCORE_BLOCKS, 256, 0, stream>>>(
        user, item_i, item_j, embed_user, embed_item, b2tab, b3tab, sback,
        out, B, SCORE_BLOCKS * 4);
}